// Round 6
// baseline (170.874 us; speedup 1.0000x reference)
//
#include <hip/hip_runtime.h>
#include <hip/hip_fp16.h>

#define IN_UNITS 256
#define H1 128
#define H2 64

typedef _Float16 f16x8 __attribute__((ext_vector_type(8)));
typedef _Float16 f16x2 __attribute__((ext_vector_type(2)));
typedef float f32x4 __attribute__((ext_vector_type(4)));

union HV { uint4 u; f16x8 v; };

static __device__ __forceinline__ unsigned short h2bits(_Float16 x) {
    union { _Float16 h; unsigned short u; } c; c.h = x; return c.u;
}

#define KEEP4(q) asm volatile("" : "+v"(q.x), "+v"(q.y), "+v"(q.z), "+v"(q.w))

// ---------------- K0: pack W2 + W1 into fp16 MFMA B-fragment order ----------
// W2 frag f = ks*4+nt (ks<4): lane l elem j = W2[ks*32 + (l>>4)*8 + j][nt*16 + (l&15)]
// W1 frag f = side*64 + ks*8 + ch*4 + nt (ks<8): col = ch*64 + nt*16 + (l&15)
__global__ __launch_bounds__(256) void pack_kernel(
    const float* __restrict__ W1, const float* __restrict__ W2,
    uint4* __restrict__ w1pack, uint4* __restrict__ w2pack)
{
    int b = blockIdx.x, t = threadIdx.x;
    if (b < 4) {
        int item = b * 256 + t;              // 0..1023
        int f = item >> 6, l = item & 63;
        int ks = f >> 2, nt = f & 3;
        int row0 = ks * 32 + (l >> 4) * 8;
        int col  = nt * 16 + (l & 15);
        unsigned short h[8];
        #pragma unroll
        for (int j = 0; j < 8; ++j)
            h[j] = h2bits((_Float16)W2[(size_t)(row0 + j) * H2 + col]);
        uint4 v;
        v.x = (unsigned)h[0] | ((unsigned)h[1] << 16);
        v.y = (unsigned)h[2] | ((unsigned)h[3] << 16);
        v.z = (unsigned)h[4] | ((unsigned)h[5] << 16);
        v.w = (unsigned)h[6] | ((unsigned)h[7] << 16);
        w2pack[item] = v;
    } else {
        int idx = (b - 4) * 256 + t;         // 0..8191
        int l = idx & 63, f = idx >> 6;      // f 0..127
        int nt = f & 3, ch = (f >> 2) & 1, ks = (f >> 3) & 7, side = f >> 6;
        int row0 = side * IN_UNITS + ks * 32 + (l >> 4) * 8;
        int col  = ch * 64 + nt * 16 + (l & 15);
        unsigned short h[8];
        #pragma unroll
        for (int j = 0; j < 8; ++j)
            h[j] = h2bits((_Float16)W1[(size_t)(row0 + j) * H1 + col]);
        uint4 v;
        v.x = (unsigned)h[0] | ((unsigned)h[1] << 16);
        v.y = (unsigned)h[2] | ((unsigned)h[3] << 16);
        v.z = (unsigned)h[4] | ((unsigned)h[5] << 16);
        v.w = (unsigned)h[6] | ((unsigned)h[7] << 16);
        w1pack[idx] = v;
    }
}

// ---------------- K1: node projections via fp16 MFMA, no LDS ----------------
// block = mtile; wave w: side = w>>1, ch = w&1. One 16-row x 64-col tile per wave.
__global__ __launch_bounds__(256) __attribute__((amdgpu_waves_per_eu(2, 2)))
void proj_kernel(
    const float* __restrict__ drug_feat, const float* __restrict__ dis_feat,
    const uint4* __restrict__ w1pack, const float* __restrict__ b1,
    unsigned short* __restrict__ drug_h, unsigned short* __restrict__ dis_h,
    int n_rows)
{
    int t = threadIdx.x, lane = t & 63, wave = t >> 6;
    int side = wave >> 1, ch = wave & 1;
    int mtile = blockIdx.x;
    const float* feat = side ? dis_feat : drug_feat;
    unsigned short* outb = side ? dis_h : drug_h;

    int row = mtile * 16 + (lane & 15);
    if (row >= n_rows) row = n_rows - 1;
    int kb = (lane >> 4) * 8;

    // prefetch the whole feat strip for this lane: 8 ks x 8 floats
    float4 fx[16];
    #pragma unroll
    for (int i = 0; i < 16; ++i)
        fx[i] = *(const float4*)(feat + (size_t)row * IN_UNITS + (i >> 1) * 32 + kb + (i & 1) * 4);

    int fbase = side * 64 + ch * 4;
    f32x4 acc[4];
    #pragma unroll
    for (int nt = 0; nt < 4; ++nt) acc[nt] = (f32x4){0.f, 0.f, 0.f, 0.f};

    #pragma unroll
    for (int ks = 0; ks < 8; ++ks) {
        float4 x0 = fx[ks * 2], x1 = fx[ks * 2 + 1];
        f16x8 a;
        a[0] = (_Float16)x0.x; a[1] = (_Float16)x0.y;
        a[2] = (_Float16)x0.z; a[3] = (_Float16)x0.w;
        a[4] = (_Float16)x1.x; a[5] = (_Float16)x1.y;
        a[6] = (_Float16)x1.z; a[7] = (_Float16)x1.w;
        #pragma unroll
        for (int nt = 0; nt < 4; ++nt) {
            HV bb; bb.u = w1pack[(size_t)(fbase + ks * 8 + nt) * 64 + lane];
            acc[nt] = __builtin_amdgcn_mfma_f32_16x16x32_f16(a, bb.v, acc[nt], 0, 0, 0);
        }
    }

    #pragma unroll
    for (int nt = 0; nt < 4; ++nt) {
        int col = ch * 64 + nt * 16 + (lane & 15);
        float bb = side ? b1[col] : 0.f;
        #pragma unroll
        for (int r = 0; r < 4; ++r) {
            int rr = mtile * 16 + (lane >> 4) * 4 + r;
            if (rr < n_rows)
                outb[(size_t)rr * H1 + col] = h2bits((_Float16)(acc[nt][r] + bb));
        }
    }
}

// ---------------- K2: per-edge MLP via fp16 MFMA, LDS-staged W2 -------------
// 256 threads = 4 waves; 32 edges/wave; 128 edges/block
__global__ __launch_bounds__(256) __attribute__((amdgpu_waves_per_eu(3, 3)))
void edge_kernel(
    const unsigned short* __restrict__ drug_h, const unsigned short* __restrict__ dis_h,
    const int* __restrict__ src_idx, const int* __restrict__ dst_idx,
    const uint4* __restrict__ w2pack, const float* __restrict__ b2,
    const float* __restrict__ W3, const float* __restrict__ b3,
    float* __restrict__ out, int n_edges)
{
    __shared__ uint4 w2s[1024];   // 16 KB: [frag = ks*4+nt][lane]

    int t = threadIdx.x, lane = t & 63, wave = t >> 6;
    int e0 = (blockIdx.x * 4 + wave) * 32;
    int emax = n_edges - 1;

    // 1) edge indices (clamped; stores are guarded later)
    int i0 = e0 + (lane & 15);      if (i0 > emax) i0 = emax;
    int i1 = e0 + 16 + (lane & 15); if (i1 > emax) i1 = emax;
    int s0 = src_idx[i0], d0 = dst_idx[i0];
    int s1 = src_idx[i1], d1 = dst_idx[i1];

    // 2) issue ALL 16 gathers; keep-alive pins them in flight together
    int kb = (lane >> 4) * 8;
    const uint4* pa0 = (const uint4*)(drug_h + s0 * H1 + kb);
    const uint4* pc0 = (const uint4*)(dis_h  + d0 * H1 + kb);
    const uint4* pa1 = (const uint4*)(drug_h + s1 * H1 + kb);
    const uint4* pc1 = (const uint4*)(dis_h  + d1 * H1 + kb);
    uint4 ga0[4], gc0[4], ga1[4], gc1[4];
    #pragma unroll
    for (int ks = 0; ks < 4; ++ks) {
        ga0[ks] = pa0[ks * 4];
        gc0[ks] = pc0[ks * 4];
        ga1[ks] = pa1[ks * 4];
        gc1[ks] = pc1[ks * 4];
    }

    // 3) epilogue constants (L2-hot)
    float b2v[4], w3v[4];
    #pragma unroll
    for (int nt = 0; nt < 4; ++nt) {
        int col = (lane & 15) + nt * 16;
        b2v[nt] = b2[col];
        w3v[nt] = W3[col];
    }
    float b3v = b3[0];

    // 4) stage W2 frags to LDS (coalesced)
    #pragma unroll
    for (int i = 0; i < 4; ++i) w2s[i * 256 + t] = w2pack[i * 256 + t];

    #pragma unroll
    for (int ks = 0; ks < 4; ++ks) { KEEP4(ga0[ks]); KEEP4(gc0[ks]); KEEP4(ga1[ks]); KEEP4(gc1[ks]); }
    __syncthreads();

    f32x4 acc[2][4];
    #pragma unroll
    for (int mt = 0; mt < 2; ++mt)
        #pragma unroll
        for (int nt = 0; nt < 4; ++nt)
            acc[mt][nt] = (f32x4){0.f, 0.f, 0.f, 0.f};

    #pragma unroll
    for (int ks = 0; ks < 4; ++ks) {
        HV a0, c0, a1, c1;
        a0.u = ga0[ks]; c0.u = gc0[ks];
        a1.u = ga1[ks]; c1.u = gc1[ks];
        f16x8 zero = (f16x8)(_Float16)0;
        f16x8 r0v = __builtin_elementwise_max(a0.v + c0.v, zero);  // v_pk_add/max_f16
        f16x8 r1v = __builtin_elementwise_max(a1.v + c1.v, zero);
        #pragma unroll
        for (int nt = 0; nt < 4; ++nt) {
            HV bb; bb.u = w2s[(ks * 4 + nt) * 64 + lane];
            acc[0][nt] = __builtin_amdgcn_mfma_f32_16x16x32_f16(r0v, bb.v, acc[0][nt], 0, 0, 0);
            acc[1][nt] = __builtin_amdgcn_mfma_f32_16x16x32_f16(r1v, bb.v, acc[1][nt], 0, 0, 0);
        }
    }

    // epilogue: out[e] = relu(h2 + b2) . W3 + b3
    // acc[mt][nt][r] = h2[edge = mt*16 + (lane>>4)*4 + r][col = (lane&15) + 16*nt]
    #pragma unroll
    for (int mt = 0; mt < 2; ++mt) {
        float part[4];
        #pragma unroll
        for (int r = 0; r < 4; ++r) {
            float p = 0.f;
            #pragma unroll
            for (int nt = 0; nt < 4; ++nt)
                p += fmaxf(acc[mt][nt][r] + b2v[nt], 0.f) * w3v[nt];
            part[r] = p;
        }
        #pragma unroll
        for (int off = 1; off <= 8; off <<= 1)
            #pragma unroll
            for (int r = 0; r < 4; ++r)
                part[r] += __shfl_xor(part[r], off, 64);
        if ((lane & 15) == 0) {
            #pragma unroll
            for (int r = 0; r < 4; ++r) {
                int e = e0 + mt * 16 + (lane >> 4) * 4 + r;
                if (e < n_edges) out[e] = part[r] + b3v;
            }
        }
    }
}

extern "C" void kernel_launch(void* const* d_in, const int* in_sizes, int n_in,
                              void* d_out, int out_size, void* d_ws, size_t ws_size,
                              hipStream_t stream) {
    const float* drug_feat = (const float*)d_in[0];
    const float* dis_feat  = (const float*)d_in[1];
    const int*   src_idx   = (const int*)d_in[2];
    const int*   dst_idx   = (const int*)d_in[3];
    const float* W1 = (const float*)d_in[4];
    const float* b1 = (const float*)d_in[5];
    const float* W2 = (const float*)d_in[6];
    const float* b2 = (const float*)d_in[7];
    const float* W3 = (const float*)d_in[8];
    const float* b3 = (const float*)d_in[9];
    float* out = (float*)d_out;

    int n_edges = in_sizes[2];
    int n_drug = in_sizes[0] / IN_UNITS;

    // ws layout: [w2pack 16KB @0][w1pack 128KB @32K][drug_h @192K][dis_h]
    uint4* w2pack = (uint4*)d_ws;
    uint4* w1pack = (uint4*)((char*)d_ws + 32 * 1024);
    unsigned short* drug_h = (unsigned short*)((char*)d_ws + 192 * 1024);
    unsigned short* dis_h  = drug_h + (size_t)n_drug * H1;

    pack_kernel<<<36, 256, 0, stream>>>(W1, W2, w1pack, w2pack);

    int mtiles = (n_drug + 15) / 16;                // 625
    proj_kernel<<<mtiles, 256, 0, stream>>>(
        drug_feat, dis_feat, w1pack, b1, drug_h, dis_h, n_drug);

    int edge_blocks = (n_edges + 127) / 128;        // 7813
    edge_kernel<<<edge_blocks, 256, 0, stream>>>(
        drug_h, dis_h, src_idx, dst_idx, w2pack, b2, W3, b3, out, n_edges);
}